// Round 6
// baseline (4567.549 us; speedup 1.0000x reference)
//
#include <hip/hip_runtime.h>
#include <math.h>

// ---------------------------------------------------------------------------
// DisableGateLSTM R10: R9 core + {b128 partial stores, gate-fused reduce,
// x(8..15)-under-poll}. 256 blocks x 512 threads, 1 block/CU. 4 groups x 64
// blocks; group g owns chains [16g,16g+16); block j owns units [8j,8j+8).
//
// R9 post-mortem: spills dead (VGPR 64, WRITE 70MB) but dur 4330us ~= R4's
// 4494 despite halving GEMM LDS reads -> step is latency/issue-bound, not
// LDS-pipe-bound. R10 cuts exposed work without touching the verified core:
//  1) sPart layout [rank][ci*4+ri]: writer emits 16 ds_write_b128 instead
//     of 64 scattered ds_write_b32 (8 writers x stride 68 -> bank-quad
//     starts 4 apart -> conflict-free).
//  2) Cross-wave reduce fused into the gate phase: gate thread (u,ch) sums
//     its 32 partials directly from sPart (<=2-way bank aliasing = free),
//     SAME order (bias + w ascending) -> bit-identical. Kills the sG
//     roundtrip and one __syncthreads.
//  3) x-part GEMM for chains 8..15 (accA[4][8] = 32 regs, spill-safe) runs
//     BEFORE the gen poll; x_t is staged at the END of step t-1 behind the
//     arrival barrier. Chains 0..7 stay fully fused (x then h, R9 order).
// Per-output FMA order identical to R9 -> absmax 0.0 preserved.
//
//  * Weights in VGPRs (48 floats/thread, zero redundancy). 48 b128 LDS
//    reads/thread/step. 64-way k-split folded 8x in-wave via 3 DPP adds.
//  * PRS=68: ranks on distinct bank quads -- do NOT change without
//    re-deriving banks.
// Cross-block h exchange: relaxed agent-scope atomics, cnt/gen monotonic
// barrier (R1-proven). Gates use exact libm expf/tanhf.
// ---------------------------------------------------------------------------

#define BATCH   64
#define SEQ     512
#define EMBED   256
#define HIDDEN  512
#define GD      768
#define CLASSES 4

#define NBLK    256
#define NTHR    512
#define GROUPS  4
#define GB      64
#define CPG     16
#define UPB     8
#define ROWS    32

// LDS strides (floats)
#define SHS  520   // sH chain stride: 512 + 8 (odd bank-quad phase per chain)
#define SXS  264   // sX chain stride: 256 + 8
#define PRS  68    // partial-scratch rank stride: 64 data + 4 pad

typedef unsigned long long __attribute__((may_alias)) ull_a;

union F2U { float f[2]; unsigned long long u; };

// Sum over each aligned 8-lane group via DPP involutions (VALU pipe, no LDS).
// half_mirror pairs (i,7-i), then quad xor2, xor1 -> every lane holds the sum.
__device__ __forceinline__ float dpp8_sum(float v) {
  int x;
  x = __builtin_amdgcn_update_dpp(0, __float_as_int(v), 0x141, 0xF, 0xF, false); // row_half_mirror
  v += __int_as_float(x);
  x = __builtin_amdgcn_update_dpp(0, __float_as_int(v), 0x4E,  0xF, 0xF, false); // quad_perm(2,3,0,1)
  v += __int_as_float(x);
  x = __builtin_amdgcn_update_dpp(0, __float_as_int(v), 0xB1,  0xF, 0xF, false); // quad_perm(1,0,3,2)
  v += __int_as_float(x);
  return v;
}

__global__ __launch_bounds__(NTHR) void lstm_persistent(
    const int*   __restrict__ ids,
    const float* __restrict__ emb,
    const float* __restrict__ Wf, const float* __restrict__ bf,
    const float* __restrict__ Wi, const float* __restrict__ bi,
    const float* __restrict__ Wo, const float* __restrict__ bo,
    const float* __restrict__ Wc, const float* __restrict__ bc,
    const float* __restrict__ fcw,
    const float* __restrict__ fcb,
    float* __restrict__ out,
    float* __restrict__ ws)
{
  __shared__ __align__(16) float sH[CPG * SHS];      // 33.3 KB
  __shared__ __align__(16) float sX[CPG * SXS];      // 16.9 KB
  __shared__ __align__(16) float sPart[64 * PRS];    // 17.4 KB
  __shared__ float sG[ROWS][CPG];                    // 2 KB (head scratch only)
  __shared__ float sC[UPB][CPG];
  __shared__ float sM[UPB][CPG];
  __shared__ float sB[ROWS];

  const int tid = threadIdx.x;
  const int bid = blockIdx.x;
  const int g   = bid & 3;
  const int j   = bid >> 2;
  const int u0  = j * UPB;

  float*    hbufF   = ws;                                    // [2][64][512] f32
  ull_a*    hbufU   = (ull_a*)ws;                            // same, ull view
  float*    wmaxF   = ws + (size_t)2 * BATCH * HIDDEN;       // [64][512] f32
  ull_a*    wmaxU   = (ull_a*)wmaxF;
  unsigned* barArea = (unsigned*)(ws + (size_t)3 * BATCH * HIDDEN);
  unsigned* cnt     = barArea + g * 64;
  unsigned* gen     = barArea + 256 + g * 64;

  // ---- thread geometry ----
  // GEMM: rg = 4-row group (rows rg*4..rg*4+3, one gate), s = k-slice
  // (h cols [8s,8s+8), x cols [4s,4s+4)). Lane = (rg<<3)|s_low -> the 8
  // s-values of a (wave,rg) sit in one aligned 8-lane DPP group.
  const int sl = tid & 7;
  const int wv = tid >> 6;
  const int s  = sl + wv * 8;          // 0..63
  const int rg = (tid >> 3) & 7;       // 0..7

  // ---- weights -> VGPRs, once (48 floats/thread, no redundancy) ----
  float4 wh[4][2], wx4[4];
  {
    const float* Wg = (rg < 2) ? Wf : (rg < 4) ? Wi : (rg < 6) ? Wo : Wc;
    const int ub = u0 + (rg & 1) * 4;
    #pragma unroll
    for (int ri = 0; ri < 4; ++ri) {
      const float* row = Wg + (size_t)(ub + ri) * GD;
      wh[ri][0] = *(const float4*)(row + s * 8);
      wh[ri][1] = *(const float4*)(row + s * 8 + 4);
      wx4[ri]   = *(const float4*)(row + HIDDEN + s * 4);
    }
  }
  if (tid < ROWS) {
    const float* bv = (tid < 8) ? bf : (tid < 16) ? bi : (tid < 24) ? bo : bc;
    sB[tid] = bv[u0 + (tid & 7)];
  }
  if (tid < UPB * CPG) {
    ((float*)sC)[tid] = 0.0f;
    ((float*)sM)[tid] = -3.402823e38f;
  }

  // staging mapping (chain-major, 32 lanes/chain)
  const int stg_c = tid >> 5;
  const int stg_s = tid & 31;
  const int bStg  = g * CPG + stg_c;

  const float* pH = sH + s * 8;        // + ci*SHS via imm offsets
  const float* pX = sX + s * 4;

  // prefetch x_0, stage it for iteration 0's pre-poll x-GEMM
  float4 rx0, rx1;
  {
    int id0 = ids[(size_t)bStg * SEQ];
    const float4* xs = (const float4*)(emb + (size_t)id0 * EMBED);
    rx0 = xs[stg_s * 2];
    rx1 = xs[stg_s * 2 + 1];
    float* dx = sX + stg_c * SXS + stg_s * 8;
    *(float4*)dx = rx0;
    *(float4*)(dx + 4) = rx1;
  }
  __syncthreads();

  for (int t = 0; t < SEQ; ++t) {
    const int pb = t & 1;

    // ---- x-part GEMM, chains 8..15 (spill-safe 32-reg accA): runs BEFORE
    //      the gen poll so the exchange latency hides under it ----
    float accA[4][8];
    #pragma unroll
    for (int c8 = 0; c8 < 8; ++c8) {
      float4 xv = *(const float4*)(pX + (c8 + 8) * SXS);
      #pragma unroll
      for (int ri = 0; ri < 4; ++ri) {
        float t0;
        t0 = wx4[ri].x * xv.x;
        t0 = fmaf(wx4[ri].y, xv.y, t0);
        t0 = fmaf(wx4[ri].z, xv.z, t0);
        t0 = fmaf(wx4[ri].w, xv.w, t0);
        accA[ri][c8] = t0;
      }
    }

    // ---- wait for h_t (relaxed poll; no cache maintenance) ----
    if (tid == 0) {
      while (__hip_atomic_load(gen, __ATOMIC_RELAXED, __HIP_MEMORY_SCOPE_AGENT)
             < (unsigned)t)
        __builtin_amdgcn_s_sleep(1);
    }
    __atomic_signal_fence(__ATOMIC_ACQUIRE);
    __syncthreads();                                   // B1

    // ---- stage h_t via coherent loads ----
    {
      const ull_a* hs = hbufU + ((size_t)pb * BATCH + bStg) * (HIDDEN / 2);
      float* dh = sH + stg_c * SHS;
      #pragma unroll
      for (int kk = 0; kk < 8; ++kk) {
        unsigned long long v = __hip_atomic_load(hs + stg_s + kk * 32,
                                                 __ATOMIC_RELAXED,
                                                 __HIP_MEMORY_SCOPE_AGENT);
        *(ull_a*)(dh + 2 * stg_s + 64 * kk) = v;
      }
    }
    __syncthreads();                                   // B2

    // ---- fused x+h GEMM + DPP k-reduce + b128 partial store, chains 0..7
    //      (FMA order identical to R9: x.x..w then h0..h1) ----
    #pragma unroll
    for (int ci = 0; ci < 8; ++ci) {
      float4 xv = *(const float4*)(pX + ci * SXS);
      float4 h0 = *(const float4*)(pH + ci * SHS);
      float4 h1 = *(const float4*)(pH + ci * SHS + 4);
      float a[4];
      #pragma unroll
      for (int ri = 0; ri < 4; ++ri) {
        float t0;
        t0 = wx4[ri].x * xv.x;
        t0 = fmaf(wx4[ri].y, xv.y, t0);
        t0 = fmaf(wx4[ri].z, xv.z, t0);
        t0 = fmaf(wx4[ri].w, xv.w, t0);
        t0 = fmaf(wh[ri][0].x, h0.x, t0);
        t0 = fmaf(wh[ri][0].y, h0.y, t0);
        t0 = fmaf(wh[ri][0].z, h0.z, t0);
        t0 = fmaf(wh[ri][0].w, h0.w, t0);
        t0 = fmaf(wh[ri][1].x, h1.x, t0);
        t0 = fmaf(wh[ri][1].y, h1.y, t0);
        t0 = fmaf(wh[ri][1].z, h1.z, t0);
        t0 = fmaf(wh[ri][1].w, h1.w, t0);
        a[ri] = dpp8_sum(t0);
      }
      if ((tid & 7) == 0)
        *(float4*)(sPart + (tid >> 3) * PRS + ci * 4) =
            make_float4(a[0], a[1], a[2], a[3]);
    }
    // ---- h-part + DPP + store, chains 8..15 (x already in accA) ----
    #pragma unroll
    for (int c8 = 0; c8 < 8; ++c8) {
      const int ci = c8 + 8;
      float4 h0 = *(const float4*)(pH + ci * SHS);
      float4 h1 = *(const float4*)(pH + ci * SHS + 4);
      float a[4];
      #pragma unroll
      for (int ri = 0; ri < 4; ++ri) {
        float t0 = accA[ri][c8];
        t0 = fmaf(wh[ri][0].x, h0.x, t0);
        t0 = fmaf(wh[ri][0].y, h0.y, t0);
        t0 = fmaf(wh[ri][0].z, h0.z, t0);
        t0 = fmaf(wh[ri][0].w, h0.w, t0);
        t0 = fmaf(wh[ri][1].x, h1.x, t0);
        t0 = fmaf(wh[ri][1].y, h1.y, t0);
        t0 = fmaf(wh[ri][1].z, h1.z, t0);
        t0 = fmaf(wh[ri][1].w, h1.w, t0);
        a[ri] = dpp8_sum(t0);
      }
      if ((tid & 7) == 0)
        *(float4*)(sPart + (tid >> 3) * PRS + ci * 4) =
            make_float4(a[0], a[1], a[2], a[3]);
    }

    // ---- prefetch x_{t+1} (latency hides under gate phase) ----
    {
      const int tn = (t + 1 < SEQ) ? t + 1 : SEQ - 1;
      int idn = ids[(size_t)bStg * SEQ + tn];
      const float4* xs = (const float4*)(emb + (size_t)idn * EMBED);
      rx0 = xs[stg_s * 2];
      rx1 = xs[stg_s * 2 + 1];
    }
    __syncthreads();                                   // B3 (sPart ready)

    // ---- gates: fused sPart reduce (same order: bias + w ascending),
    //      nonlinearity, state update, coherent h store ----
    if (tid < 128) {
      const int u = tid & 7, ch = tid >> 3;
      const int rgb = u >> 2, ril = u & 3;
      float pre[4];
      #pragma unroll
      for (int gi = 0; gi < 4; ++gi) {
        float ssum = sB[gi * 8 + u];
        #pragma unroll
        for (int w = 0; w < 8; ++w)
          ssum += sPart[(w * 8 + gi * 2 + rgb) * PRS + ch * 4 + ril];
        pre[gi] = ssum;
      }
      float f  = 1.0f / (1.0f + expf(-pre[0]));
      float i_ = 1.0f / (1.0f + expf(-pre[1]));
      float o  = 1.0f / (1.0f + expf(-pre[2]));
      float gg = tanhf(pre[3]);
      float cn = f * sC[u][ch] + i_ * gg;
      float h  = o * tanhf(cn);
      sC[u][ch] = cn;
      sM[u][ch] = fmaxf(sM[u][ch], h);
      __hip_atomic_store(
          hbufF + ((size_t)(pb ^ 1) * BATCH + g * CPG + ch) * HIDDEN + u0 + u,
          h, __ATOMIC_RELAXED, __HIP_MEMORY_SCOPE_AGENT);
    }
    // ---- stage x_{t+1} for the next iteration's pre-poll x-GEMM ----
    {
      float* dx = sX + stg_c * SXS + stg_s * 8;
      *(float4*)dx = rx0;
      *(float4*)(dx + 4) = rx1;
    }
    __syncthreads();   // B4: drains vmcnt -> h stores coherence-visible;
                       //     also orders sX writes before next pre-poll reads

    // ---- arrival: monotonic count (never reset) ----
    if (tid == 0) {
      unsigned old = __hip_atomic_fetch_add(cnt, 1u, __ATOMIC_RELAXED,
                                            __HIP_MEMORY_SCOPE_AGENT);
      if (old == (unsigned)((t + 1) * GB - 1))
        __hip_atomic_store(gen, (unsigned)(t + 1), __ATOMIC_RELAXED,
                           __HIP_MEMORY_SCOPE_AGENT);
    }
  }

  // ---- publish running max (coherent), final barrier ----
  if (tid < 128) {
    const int u = tid & 7, ch = tid >> 3;
    __hip_atomic_store(wmaxF + (size_t)(g * CPG + ch) * HIDDEN + u0 + u,
                       sM[u][ch], __ATOMIC_RELAXED, __HIP_MEMORY_SCOPE_AGENT);
  }
  __syncthreads();
  if (tid == 0) {
    unsigned old = __hip_atomic_fetch_add(cnt, 1u, __ATOMIC_RELAXED,
                                          __HIP_MEMORY_SCOPE_AGENT);
    if (old == (unsigned)((SEQ + 1) * GB - 1))
      __hip_atomic_store(gen, (unsigned)(SEQ + 1), __ATOMIC_RELAXED,
                         __HIP_MEMORY_SCOPE_AGENT);
  }

  // ---- head GEMV on group-leader blocks ----
  if (j == 0) {
    if (tid == 0) {
      while (__hip_atomic_load(gen, __ATOMIC_RELAXED, __HIP_MEMORY_SCOPE_AGENT)
             < (unsigned)(SEQ + 1))
        __builtin_amdgcn_s_sleep(1);
    }
    __atomic_signal_fence(__ATOMIC_ACQUIRE);
    __syncthreads();

    const int ch = tid & 15, cls = (tid >> 4) & 3, us = tid >> 6;
    const ull_a* mrow = wmaxU + (size_t)(g * CPG + ch) * (HIDDEN / 2) + us * 32;
    const float* wrow = fcw + (size_t)cls * HIDDEN + us * 64;
    float sacc = 0.0f;
    for (int q = 0; q < 32; ++q) {
      F2U v;
      v.u = __hip_atomic_load(mrow + q, __ATOMIC_RELAXED,
                              __HIP_MEMORY_SCOPE_AGENT);
      sacc = fmaf(v.f[0], wrow[2 * q], sacc);
      sacc = fmaf(v.f[1], wrow[2 * q + 1], sacc);
    }
    float* red2 = &sG[0][0];
    red2[tid] = sacc;
    __syncthreads();
    if (tid < 64) {
      float tot = fcb[(tid >> 4) & 3];
      #pragma unroll
      for (int q = 0; q < 8; ++q) tot += red2[q * 64 + tid];
      out[(g * CPG + (tid & 15)) * CLASSES + ((tid >> 4) & 3)] = tot;
    }
  }
}

extern "C" void kernel_launch(void* const* d_in, const int* in_sizes, int n_in,
                              void* d_out, int out_size, void* d_ws, size_t ws_size,
                              hipStream_t stream) {
  const int*   ids = (const int*)  d_in[0];
  const float* emb = (const float*)d_in[1];
  const float* Wf  = (const float*)d_in[2];
  const float* bf  = (const float*)d_in[3];
  const float* Wi  = (const float*)d_in[4];
  const float* bi  = (const float*)d_in[5];
  const float* Wo  = (const float*)d_in[6];
  const float* bo  = (const float*)d_in[7];
  const float* Wc  = (const float*)d_in[8];
  const float* bc  = (const float*)d_in[9];
  const float* fcw = (const float*)d_in[10];
  const float* fcb = (const float*)d_in[11];

  // zero h0 (hbuf buffer 0) and the barrier counters
  hipMemsetAsync(d_ws, 0, (size_t)BATCH * HIDDEN * sizeof(float), stream);
  hipMemsetAsync((char*)d_ws + (size_t)3 * BATCH * HIDDEN * sizeof(float),
                 0, 4096, stream);

  lstm_persistent<<<dim3(NBLK), dim3(NTHR), 0, stream>>>(
      ids, emb, Wf, bf, Wi, bi, Wo, bo, Wc, bc, fcw, fcb,
      (float*)d_out, (float*)d_ws);
}